// Round 3
// baseline (182.698 us; speedup 1.0000x reference)
//
#include <hip/hip_runtime.h>

// Problem constants (GCNLayer_13357348290889): B=4, N=50000, CIN=64, HALF=32.
#define B_    4
#define N_    50000
#define CIN_  64
#define HALF_ 32
#define NFB_  196      // fill blocks: ceil(E / FILL_T)
#define FILL_T 4096    // edges per fill block
#define SB_   782      // sort buckets of 64 rows: fb = row >> 6
#define SCAP_ 1536     // records per bucket (mean 1024, sd 32 -> +16 sigma)
#define TBLK_ 3125     // transform blocks (200000 nodes / 64)

// fp32 -> bf16 round-to-nearest-even (inputs are finite normals)
static __device__ __forceinline__ unsigned short f2bf(float f) {
    unsigned u = __float_as_uint(f);
    return (unsigned short)((u + 0x7FFFu + ((u >> 16) & 1u)) >> 16);
}

// ---------------------------------------------------------------------------
// mega1: grid-fused transform (blocks NFB_..NFB_+3124) + fill (blocks 0..195).
// transform: out[:,32:64] = Weye@x + beye ; y(bf16,[n][b][32]) = Wlin@x
// fill: bin edges into 782 buckets (64 rows each) of block-exclusive
// grouped ranges. Record: int2( col | (row<<16), f32 val ).
// cbcursor must be zeroed by a preceding memset.
//
// R3 changes (counter-driven):
//  - fill/transform LDS arrays UNIONed: block LDS 43.5KB -> 34.8KB
//    (3 -> 4 blocks/CU; occupancy was 23.6%).
//  - xs node stride padded 64 -> 68 floats: X-read 4-way bank conflict
//    (stride 1024B, same bank) -> 2-way (free).
//  - WtT fill re-tiled to (16c x 4o) per wave-instr: write bank
//    (4c+o)%32 all-distinct x2 -> conflict-free (was 8-way).
// ---------------------------------------------------------------------------
struct FillS { int hist[SB_]; int res[SB_]; int lcur[SB_]; };   // 9384 B
struct TrS   { float xs[64 * 68]; float WtT[64 * 68]; };        // 34816 B
union  SMemU { FillS f; TrS tr; };

__global__ __launch_bounds__(256) void mega1_kernel(
    const float* __restrict__ x,
    const float* __restrict__ Wlin,
    const float* __restrict__ Weye, const float* __restrict__ beye,
    unsigned short* __restrict__ y, float* __restrict__ out,
    const int* __restrict__ rows, const int* __restrict__ cols,
    const float* __restrict__ vals,
    int* __restrict__ cbcursor, int2* __restrict__ sEdge1, int E)
{
    __shared__ __align__(16) SMemU sm;
    int t = threadIdx.x;

    if (blockIdx.x < NFB_) {
        // ---------------- fill part ----------------
        for (int i = t; i < SB_; i += 256) sm.f.hist[i] = 0;
        __syncthreads();

        int e0   = blockIdx.x * FILL_T;
        int eEnd = e0 + FILL_T; if (eEnd > E) eEnd = E;

        for (int e = e0 + t; e < eEnd; e += 256)
            atomicAdd(&sm.f.hist[((unsigned)rows[e]) >> 6], 1);
        __syncthreads();

        for (int i = t; i < SB_; i += 256) {
            int h = sm.f.hist[i];
            sm.f.res[i]  = h ? atomicAdd(&cbcursor[i], h) : 0;
            sm.f.lcur[i] = 0;
        }
        __syncthreads();

        for (int e = e0 + t; e < eEnd; e += 256) {
            unsigned r = (unsigned)rows[e];
            int fb = r >> 6;
            int p  = sm.f.res[fb] + atomicAdd(&sm.f.lcur[fb], 1);
            if (p < SCAP_)
                sEdge1[(size_t)fb * SCAP_ + p] =
                    make_int2((int)(((unsigned)cols[e]) | (r << 16)),
                              __float_as_int(vals[e]));
        }
        return;
    }

    // ---------------- transform part ----------------
    int tb = blockIdx.x - NFB_;                    // 0..3124

    // stage x tile: node-major, stride 17 float4 (68 floats)
    const float4* xg4 = (const float4*)x + (size_t)tb * 1024;
    float4* xs4 = (float4*)sm.tr.xs;
#pragma unroll
    for (int i0 = 0; i0 < 4; ++i0) {
        int i = t + 256 * i0;
        xs4[(i >> 4) * 17 + (i & 15)] = xg4[i];
    }

    // stage W^T: per wave-instr a (16c x 4o) tile -> conflict-free writes
#pragma unroll
    for (int k = 0; k < 16; ++k) {
        int m = (t >> 6) * 16 + k;                 // tile 0..63
        int o = (m & 15) * 4 + ((t >> 4) & 3);
        int c = (m >> 4) * 16 + (t & 15);
        float w = (o < 32) ? Wlin[o * 64 + c] : Weye[(o - 32) * 64 + c];
        sm.tr.WtT[c * 68 + o] = w;
    }
    __syncthreads();

    int nq = t >> 4;                 // 4-node group
    int oq = t & 15;                 // 4-output group
    float4 acc[4];
    acc[0] = acc[1] = acc[2] = acc[3] = make_float4(0.f, 0.f, 0.f, 0.f);

    for (int cs = 0; cs < 16; ++cs) {
        float4 X[4];
#pragma unroll
        for (int n = 0; n < 4; ++n)
            X[n] = xs4[(nq * 4 + n) * 17 + cs];
#pragma unroll
        for (int j = 0; j < 4; ++j) {
            float4 W = *(const float4*)&sm.tr.WtT[(4 * cs + j) * 68 + 4 * oq];
#pragma unroll
            for (int n = 0; n < 4; ++n) {
                float xv = (&X[n].x)[j];
                acc[n].x = fmaf(xv, W.x, acc[n].x);
                acc[n].y = fmaf(xv, W.y, acc[n].y);
                acc[n].z = fmaf(xv, W.z, acc[n].z);
                acc[n].w = fmaf(xv, W.w, acc[n].w);
            }
        }
    }

    int flat0 = tb * 64 + nq * 4;
    if (oq < 8) {                    // lin outputs -> y (bf16, [n][b][32])
        ushort4* y4 = (ushort4*)y;
#pragma unroll
        for (int n = 0; n < 4; ++n) {
            int flat = flat0 + n;
            int b  = flat / N_;
            int nn = flat - b * N_;
            ushort4 pk;
            pk.x = f2bf(acc[n].x); pk.y = f2bf(acc[n].y);
            pk.z = f2bf(acc[n].z); pk.w = f2bf(acc[n].w);
            y4[(size_t)nn * 32 + b * 8 + oq] = pk;
        }
    } else {                         // eye outputs -> out[:,32:64] + bias
        const float4 be = ((const float4*)beye)[oq - 8];
        float4* out4 = (float4*)out;
#pragma unroll
        for (int n = 0; n < 4; ++n)
            out4[(size_t)(flat0 + n) * 16 + 8 + (oq - 8)] =
                make_float4(acc[n].x + be.x, acc[n].y + be.y,
                            acc[n].z + be.z, acc[n].w + be.w);
    }
}

// ---------------------------------------------------------------------------
// sortgather: one 256-thread block (4 waves) per 64-row bucket.
// Phase A: cache <=6 records/thread in registers (single global read) +
// LDS row histogram. Phase B: 64-bin scan by wave 0 via shfl_up. Phase C:
// scatter 4B records (bf16 val | col) into LDS. Phase D: 4 waves x 16 rows;
// per edge one coalesced yu dword per lane, records broadcast from LDS,
// register accumulate. out[b,n,0:32] = b_lin + sum. No f32 atomics.
// ---------------------------------------------------------------------------
__global__ __launch_bounds__(256) void sortgather_kernel(
    const int2* __restrict__ sEdge1, const int* __restrict__ cbcursor,
    const unsigned int* __restrict__ yu, const float* __restrict__ blin,
    float* __restrict__ out)
{
    __shared__ int hist[64], cur[64], rs_s[64], rs_e[64];
    __shared__ unsigned int sorted[SCAP_];         // 6 KB

    int t = threadIdx.x, fb = blockIdx.x;
    int cnt = cbcursor[fb]; if (cnt > SCAP_) cnt = SCAP_;
    const int2* src = sEdge1 + (size_t)fb * SCAP_;

    if (t < 64) hist[t] = 0;
    __syncthreads();

    // Phase A: register-cache records (static indexing) + histogram
    int2 rc[6];
#pragma unroll
    for (int u = 0; u < 6; ++u) {
        int i = t + 256 * u;
        if (i < cnt) {
            rc[u] = src[i];
            atomicAdd(&hist[(((unsigned)rc[u].x) >> 16) & 63u], 1);
        }
    }
    __syncthreads();

    // Phase B: 64-bin inclusive scan in wave 0 (6 shfl steps)
    if (t < 64) {
        int v = hist[t], s = v;
#pragma unroll
        for (int d = 1; d < 64; d <<= 1) {
            int tv = __shfl_up(s, d, 64);
            if (t >= d) s += tv;
        }
        cur[t] = s - v; rs_s[t] = s - v; rs_e[t] = s;
    }
    __syncthreads();

    // Phase C: scatter from registers into row-grouped LDS
#pragma unroll
    for (int u = 0; u < 6; ++u) {
        int i = t + 256 * u;
        if (i < cnt) {
            int2 w = rc[u];
            int rl = (((unsigned)w.x) >> 16) & 63;
            int p  = atomicAdd(&cur[rl], 1);
            sorted[p] = ((unsigned)f2bf(__int_as_float(w.y)) << 16)
                      | (((unsigned)w.x) & 0xFFFFu);
        }
    }
    __syncthreads();

    // Phase D: gather
    int wv = t >> 6, lane = t & 63;
    int b  = lane >> 4;
    int c0 = (lane & 15) * 2;
    float bl0 = blin[c0], bl1 = blin[c0 + 1];

    for (int r = wv * 16; r < wv * 16 + 16; ++r) {
        int n = fb * 64 + r;
        if (n >= N_) break;
        int st = rs_s[r], en = rs_e[r];
        float a0 = 0.f, a1 = 0.f;
        for (int j = st; j < en; j += 8) {
            unsigned rec[8];
#pragma unroll
            for (int u = 0; u < 8; ++u) {
                int idx = j + u;
                unsigned rr = sorted[idx < en ? idx : en - 1];
                if (idx >= en) rr &= 0xFFFFu;      // zero val -> exact no-op
                rec[u] = rr;
            }
            unsigned w4[8];
#pragma unroll
            for (int u = 0; u < 8; ++u)
                w4[u] = yu[(size_t)(rec[u] & 0xFFFFu) * 64 + lane];
#pragma unroll
            for (int u = 0; u < 8; ++u) {
                float vv = __uint_as_float(rec[u] & 0xFFFF0000u);
                a0 = fmaf(vv, __uint_as_float(w4[u] << 16), a0);
                a1 = fmaf(vv, __uint_as_float(w4[u] & 0xFFFF0000u), a1);
            }
        }
        float2 rr2;
        rr2.x = bl0 + a0;
        rr2.y = bl1 + a1;
        *(float2*)&out[((size_t)b * N_ + n) * 64 + c0] = rr2;
    }
}

// ---------------------------------------------------------------------------
// Fallback (tiny ws): atomic scatter at 64 ch + in-place transform.
// ---------------------------------------------------------------------------
__global__ __launch_bounds__(256) void scatter64_kernel(
    const float* __restrict__ x, const float* __restrict__ vals,
    const int* __restrict__ rows, const int* __restrict__ cols,
    float* __restrict__ out, int E)
{
    int idx = blockIdx.x * 256 + threadIdx.x;
    if (idx >= E * 256) return;
    int c = idx & 63, b = (idx >> 6) & 3, e = idx >> 8;
    atomicAdd(&out[((size_t)b * N_ + rows[e]) * 64 + c],
              vals[e] * x[((size_t)b * N_ + cols[e]) * 64 + c]);
}

__global__ __launch_bounds__(256) void transform_inplace_kernel(
    const float* __restrict__ x,
    const float* __restrict__ Wlin, const float* __restrict__ blin,
    const float* __restrict__ Weye, const float* __restrict__ beye,
    float* __restrict__ out, int total_nodes)
{
    __shared__ float Wt[64 * 65];
    __shared__ float bias[64];
    __shared__ float axs[4][64];
    __shared__ float xs2[4][64];
    int tid = threadIdx.x;
    for (int i = tid; i < HALF_ * CIN_; i += 256) {
        int o = i >> 6, c = i & 63;
        Wt[c * 65 + o]      = Wlin[i];
        Wt[c * 65 + o + 32] = Weye[i];
    }
    if (tid < 32) { bias[tid] = blin[tid]; bias[tid + 32] = beye[tid]; }
    __syncthreads();
    int wave = tid >> 6, lane = tid & 63;
    int node = blockIdx.x * 4 + wave;
    if (node < total_nodes) {
        axs[wave][lane] = out[node * 64 + lane];
        xs2[wave][lane] = x[node * 64 + lane];
    }
    __syncthreads();
    if (node >= total_nodes) return;
    const float* src = (lane < 32) ? axs[wave] : xs2[wave];
    float acc = bias[lane];
#pragma unroll
    for (int c = 0; c < 64; ++c) acc = fmaf(src[c], Wt[c * 65 + lane], acc);
    out[node * 64 + lane] = acc;
}

extern "C" void kernel_launch(void* const* d_in, const int* in_sizes, int n_in,
                              void* d_out, int out_size, void* d_ws, size_t ws_size,
                              hipStream_t stream) {
    const float* x    = (const float*)d_in[0];
    const float* vals = (const float*)d_in[1];
    const float* Wlin = (const float*)d_in[2];
    const float* blin = (const float*)d_in[3];
    const float* Weye = (const float*)d_in[4];
    const float* beye = (const float*)d_in[5];
    const int*   rows = (const int*)d_in[6];
    const int*   cols = (const int*)d_in[7];
    float*       out  = (float*)d_out;

    const int E = in_sizes[1];                       // 800000
    const int total_nodes = B_ * N_;                 // 200000

    // ws layout
    char* base = (char*)d_ws;
    size_t off_y      = 0;
    size_t off_edge1  = off_y     + (size_t)N_ * B_ * HALF_ * 2;   // 12.8 MB
    size_t off_cur    = off_edge1 + (size_t)SB_ * SCAP_ * 8;       // 9.61 MB
    size_t need       = off_cur   + 4096;

    if (ws_size >= need && E <= NFB_ * FILL_T) {
        unsigned short* y      = (unsigned short*)(base + off_y);
        int2*           sEdge1 = (int2*)          (base + off_edge1);
        int*            cbcur  = (int*)           (base + off_cur);

        hipMemsetAsync(cbcur, 0, SB_ * 4, stream);
        mega1_kernel<<<TBLK_ + NFB_, 256, 0, stream>>>(
            x, Wlin, Weye, beye, y, out, rows, cols, vals, cbcur, sEdge1, E);
        sortgather_kernel<<<SB_, 256, 0, stream>>>(
            sEdge1, cbcur, (const unsigned int*)y, blin, out);
    } else {
        hipMemsetAsync(d_out, 0, (size_t)out_size * sizeof(float), stream);
        scatter64_kernel<<<(E * 256 + 255) / 256, 256, 0, stream>>>(
            x, vals, rows, cols, out, E);
        transform_inplace_kernel<<<(total_nodes + 3) / 4, 256, 0, stream>>>(
            x, Wlin, blin, Weye, beye, out, total_nodes);
    }
}